// Round 8
// baseline (869.402 us; speedup 1.0000x reference)
//
#include <hip/hip_runtime.h>

#define NTHR  256
#define F     59
#define K0    29
#define NB    15
#define B     131072
#define RPB   64                 // rows per block
#define NBLK  (B / RPB)          // 2048 blocks
#define NSLC  8                  // sliced fp64 accumulators (64B line each)

// d_ws layout: acc[NB][F][NSLC][8] doubles, then hT[F][B] floats
#define ACC_PER_LAYER (F * NSLC * 8)            // 3776 doubles / layer
#define ACC_TOTAL     (NB * ACC_PER_LAYER)      // 56640 doubles = 453120 B
#define HT_OFF_B      ((size_t)ACC_TOTAL * 8)

// ---------------------------------------------------------------------------
// Finalize previous layer's stats (fp64) into LDS scale/shift (f32).
// Runs redundantly in every block; acc_prev complete by stream order.
// ---------------------------------------------------------------------------
__device__ __forceinline__ void make_scsh(const double* __restrict__ acc_prev,
                                          const float* __restrict__ g,
                                          const float* __restrict__ bt,
                                          float* scsh, int tid)
{
  if (tid < F) {
    double s1 = 0.0, s2 = 0.0;
    #pragma unroll
    for (int s = 0; s < NSLC; ++s) {
      const double* slot = acc_prev + (size_t)(tid * NSLC + s) * 8;
      s1 += slot[0];
      s2 += slot[1];
    }
    const double inv = 1.0 / (double)B;
    double mu   = s1 * inv;
    double var  = fma(s2, inv, -mu * mu);        // biased variance, fp64
    double rstd = 1.0 / sqrt(var + 1e-5);
    double sc   = rstd * (double)g[tid];
    scsh[tid]      = (float)sc;
    scsh[64 + tid] = (float)fma(-mu, sc, (double)bt[tid]);
  }
  __syncthreads();
}

// ---------------------------------------------------------------------------
// Wave stats: butterfly (sum, sumsq) of y over the wave's 64 rows; lane j
// keeps the result for local feature j.
// ---------------------------------------------------------------------------
__device__ __forceinline__ void wave_stat(float y, int j, int lane,
                                          float& ms, float& mss)
{
  float s = y, ss = y * y;
  #pragma unroll
  for (int m = 1; m < 64; m <<= 1) {
    s  += __shfl_xor(s,  m, 64);
    ss += __shfl_xor(ss, m, 64);
  }
  if (lane == j) { ms = s; mss = ss; }
}

// ---------------------------------------------------------------------------
// One Linear+ReLU layer. Block = 64 rows; wave q owns feature quarter q
// (15/15/15/14). Input rows staged in LDS (normalize-on-copy); k-outer
// matmul keeps VGPR <= 64 for 8 waves/SIMD. Stats: per-wave butterfly ->
// sliced f64 atomics directly (features disjoint across waves).
// ---------------------------------------------------------------------------
template<int K, bool FIRST>
__global__ void __launch_bounds__(NTHR, 8)
layer_kernel(const float* in, const float* __restrict__ W,
             const float* __restrict__ bvec,
             const double* __restrict__ acc_prev,    // prev stats (unless FIRST)
             const float* __restrict__ g_prev, const float* __restrict__ bt_prev,
             float* hout, double* acc)
{
  __shared__ float scsh[128];
  __shared__ float hbuf[FIRST ? (RPB * 33) : (K * RPB)];

  const int tid  = threadIdx.x;
  const int lane = tid & 63;
  const int r    = lane;                                 // row-in-block
  const int qu   = __builtin_amdgcn_readfirstlane(tid >> 6);  // wave's quarter
  const int rowbase = blockIdx.x * RPB;
  const int slice   = blockIdx.x & (NSLC - 1);

  if (!FIRST) make_scsh(acc_prev, g_prev, bt_prev, scsh, tid);

  // ---- phase 1: stage (and normalize) the block's 64 input rows ----
  if (FIRST) {
    const float* xblk = in + (size_t)rowbase * K;        // row-major x
    for (int i = tid; i < RPB * K; i += NTHR) {
      int rr = i / K, kk = i - rr * K;
      hbuf[rr * 33 + kk] = xblk[i];                      // [r][33], conflict-free
    }
  } else {
    for (int i = tid; i < K * RPB; i += NTHR) {
      int kk = i >> 6, rr = i & 63;                      // [k][64]
      hbuf[i] = fmaf(in[(size_t)kk * B + rowbase + rr], scsh[kk], scsh[64 + kk]);
    }
  }
  __syncthreads();

  // ---- per-wave W row pointers (scalar; q==3 j==14 clamps to row 58) ----
  const float* wp[15];
  float acc_[15];
  #pragma unroll
  for (int j = 0; j < 15; ++j) {
    int f = qu * 15 + j; if (f > F - 1) f = F - 1;
    wp[j]   = W + (size_t)f * K;
    acc_[j] = bvec[f];
  }

  // ---- k-outer matmul: 1 LDS read + 15 FMA per k ----
  #pragma unroll 1
  for (int k = 0; k < K; ++k) {
    float hk = FIRST ? hbuf[r * 33 + k] : hbuf[k * 64 + r];
    #pragma unroll
    for (int j = 0; j < 15; ++j)
      acc_[j] = fmaf(hk, wp[j][k], acc_[j]);
  }

  // ---- ReLU + store (coalesced) + wave stats ----
  float ms = 0.f, mss = 0.f;
  float* op = hout + rowbase + r;
  #pragma unroll
  for (int j = 0; j < 15; ++j) {
    if (qu * 15 + j < F) {                               // wave-uniform guard
      float y = fmaxf(acc_[j], 0.f);
      op[(size_t)(qu * 15 + j) * B] = y;
      wave_stat(y, j, lane, ms, mss);
    }
  }

  // ---- sliced global f64 atomics (lane j -> feature qu*15+j) ----
  if (lane < 15 && qu * 15 + lane < F) {
    double* slot = acc + ((size_t)(qu * 15 + lane) * NSLC + slice) * 8;
    atomicAdd(slot,     (double)ms);
    atomicAdd(slot + 1, (double)mss);
  }
}

// ---------------------------------------------------------------------------
// Final BN: hT -> row-major out via LDS transpose tile (64 rows/block).
// ---------------------------------------------------------------------------
__global__ void __launch_bounds__(NTHR, 8)
final_tr_kernel(const float* __restrict__ hT, const double* __restrict__ acc_last,
                const float* __restrict__ g, const float* __restrict__ bt,
                float* __restrict__ out)
{
  __shared__ float ybuf[RPB * 61];
  __shared__ float scsh[128];
  const int tid = threadIdx.x;
  make_scsh(acc_last, g, bt, scsh, tid);

  const int rowbase = blockIdx.x * RPB;
  for (int i = tid; i < F * RPB; i += NTHR) {
    int j = i >> 6, r = i & 63;
    ybuf[r * 61 + j] = fmaf(hT[(size_t)j * B + rowbase + r], scsh[j], scsh[64 + j]);
  }
  __syncthreads();

  float* oblk = out + (size_t)rowbase * F;
  for (int i = tid; i < RPB * F; i += NTHR) {
    int r = i / F, j = i - r * F;
    oblk[i] = ybuf[r * 61 + j];
  }
}

// ---------------------------------------------------------------------------
extern "C" void kernel_launch(void* const* d_in, const int* in_sizes, int n_in,
                              void* d_out, int out_size, void* d_ws, size_t ws_size,
                              hipStream_t stream)
{
  const float* x   = (const float*)d_in[0];
  const float* W0  = (const float*)d_in[1];
  const float* b0  = (const float*)d_in[2];
  const float* g0  = (const float*)d_in[3];
  const float* bt0 = (const float*)d_in[4];
  const float* Ws  = (const float*)d_in[5];
  const float* bs  = (const float*)d_in[6];
  const float* gs  = (const float*)d_in[7];
  const float* bts = (const float*)d_in[8];
  float* out = (float*)d_out;

  double* acc = (double*)d_ws;                       // [NB][F][NSLC][8]
  float*  hT  = (float*)((char*)d_ws + HT_OFF_B);    // [F][B]

  // zero the atomic accumulators every call (deterministic, capture-safe)
  hipMemsetAsync(d_ws, 0, (size_t)ACC_TOTAL * sizeof(double), stream);

  // layer 0: x[B,29] -> hT[59][B]
  layer_kernel<K0, true><<<NBLK, NTHR, 0, stream>>>(
      x, W0, b0, nullptr, nullptr, nullptr, hT, acc);

  // layers 1..14: hT -> hT (read-before-write per block), normalize-prev-on-read
  for (int b = 1; b < NB; ++b) {
    const float* gp  = (b == 1) ? g0  : gs  + (size_t)(b - 2) * F;
    const float* btp = (b == 1) ? bt0 : bts + (size_t)(b - 2) * F;
    layer_kernel<F, false><<<NBLK, NTHR, 0, stream>>>(
        hT, Ws + (size_t)(b - 1) * F * F, bs + (size_t)(b - 1) * F,
        acc + (size_t)(b - 1) * ACC_PER_LAYER, gp, btp,
        hT, acc + (size_t)b * ACC_PER_LAYER);
  }

  // apply layer 14's BN: hT -> row-major d_out
  final_tr_kernel<<<NBLK, NTHR, 0, stream>>>(
      hT, acc + (size_t)(NB - 1) * ACC_PER_LAYER,
      gs + (size_t)(NB - 2) * F, bts + (size_t)(NB - 2) * F, out);
}

// Round 9
// 846.561 us; speedup vs baseline: 1.0270x; 1.0270x over previous
//
#include <hip/hip_runtime.h>

#define NTHR  256
#define F     59
#define K0    29
#define NB    15
#define B     131072
#define RPB   64                 // rows per block
#define NBLK  (B / RPB)          // 2048 blocks
#define NSLC  16                 // atomic slices; 16B slot per (feature,slice)
#define YPAD  73                 // ytile row pad (73 mod 32 = 9, spreads banks)

// d_ws layout: acc[NB][F][NSLC][2] doubles, then hT[F][B] floats
#define ACC_PER_LAYER (F * NSLC * 2)            // 1888 doubles / layer
#define ACC_TOTAL     (NB * ACC_PER_LAYER)      // 28320 doubles = 226560 B
#define HT_OFF_B      ((size_t)ACC_TOTAL * 8)

// ---------------------------------------------------------------------------
// Finalize previous layer's stats (fp64) into LDS {scale, shift} (float2).
// Runs redundantly in every block (wave 0); acc_prev complete by stream order.
// ---------------------------------------------------------------------------
__device__ __forceinline__ void make_scsh(const double* __restrict__ acc_prev,
                                          const float* __restrict__ g,
                                          const float* __restrict__ bt,
                                          float2* scsh, int tid)
{
  if (tid < F) {
    double s1 = 0.0, s2 = 0.0;
    #pragma unroll
    for (int s = 0; s < NSLC; ++s) {
      const double* p = acc_prev + (size_t)(tid * NSLC + s) * 2;
      s1 += p[0];
      s2 += p[1];
    }
    const double inv = 1.0 / (double)B;
    double mu   = s1 * inv;
    double var  = fma(s2, inv, -mu * mu);        // biased variance, fp64
    double rstd = 1.0 / sqrt(var + 1e-5);
    double sc   = rstd * (double)g[tid];
    scsh[tid] = make_float2((float)sc, (float)fma(-mu, sc, (double)bt[tid]));
  }
  __syncthreads();
}

// ---------------------------------------------------------------------------
// One Linear+ReLU layer. Block = 64 rows (row = lane); wave q owns features
// q*15..q*15+14 (last wave 14, dup clamped). j-outer/k-inner: W rows are
// CONTIGUOUS -> batched s_load_dwordx8; h[K] in registers. Stats: y ->
// per-wave LDS tile -> 60 lanes x 16-row fp32 partials -> 2 shfl levels ->
// f64 sliced atomics. No cross-wave stats sharing (one barrier per kernel).
// ---------------------------------------------------------------------------
template<int K, bool FIRST>
__global__ void __launch_bounds__(NTHR, 4)
layer_kernel(const float* in, const float* __restrict__ W,
             const float* __restrict__ bvec,
             const double* __restrict__ acc_prev,    // prev stats (unless FIRST)
             const float* __restrict__ g_prev, const float* __restrict__ bt_prev,
             float* hout, double* acc)
{
  __shared__ float2 scsh[64];
  __shared__ float  ytile[4][15 * YPAD];             // 17520 B
  __shared__ float  xbuf[FIRST ? RPB * (K0 + 1) : 1];

  const int tid   = threadIdx.x;
  const int lane  = tid & 63;
  const int qu    = __builtin_amdgcn_readfirstlane(tid >> 6);
  const int rowbase = blockIdx.x * RPB;
  const int row     = rowbase + lane;
  const int slice   = blockIdx.x & (NSLC - 1);

  if (FIRST) {
    const float* xblk = in + (size_t)rowbase * K;
    for (int i = tid; i < RPB * K; i += NTHR) {
      int rr = i / K, kk = i - rr * K;
      xbuf[rr * (K + 1) + kk] = xblk[i];             // coalesced in, padded LDS
    }
    __syncthreads();
  } else {
    make_scsh(acc_prev, g_prev, bt_prev, scsh, tid);
  }

  // ---- input row -> registers (normalized unless FIRST) ----
  float h[K];
  if (FIRST) {
    #pragma unroll
    for (int k = 0; k < K; ++k) h[k] = xbuf[lane * (K + 1) + k];
  } else {
    #pragma unroll
    for (int k = 0; k < K; ++k) {
      float2 s = scsh[k];                            // ds_read_b64 broadcast
      h[k] = fmaf(in[(size_t)k * B + row], s.x, s.y);
    }
  }

  float* ytq = ytile[qu];
  float* op  = hout + row;
  const int fbase = qu * 15;

  // ---- j-outer (3 features), k-inner unrolled: contiguous W s_loads ----
  #pragma unroll 1
  for (int jb = 0; jb < 15; jb += 3) {
    int f0 = fbase + jb, f1 = f0 + 1, f2 = f0 + 2;
    int w0 = f0 > F - 1 ? F - 1 : f0;
    int w1 = f1 > F - 1 ? F - 1 : f1;
    int w2 = f2 > F - 1 ? F - 1 : f2;
    const float* p0 = W + (size_t)w0 * K;
    const float* p1 = W + (size_t)w1 * K;
    const float* p2 = W + (size_t)w2 * K;
    float a0 = bvec[w0], a1 = bvec[w1], a2 = bvec[w2];
    #pragma unroll
    for (int k = 0; k < K; ++k) {
      float hk = h[k];
      a0 = fmaf(hk, p0[k], a0);
      a1 = fmaf(hk, p1[k], a1);
      a2 = fmaf(hk, p2[k], a2);
    }
    a0 = fmaxf(a0, 0.f); a1 = fmaxf(a1, 0.f); a2 = fmaxf(a2, 0.f);
    if (f0 < F) op[(size_t)f0 * B] = a0;             // uniform guards
    if (f1 < F) op[(size_t)f1 * B] = a1;
    if (f2 < F) op[(size_t)f2 * B] = a2;
    ytq[(jb + 0) * YPAD + lane] = a0;
    ytq[(jb + 1) * YPAD + lane] = a1;
    ytq[(jb + 2) * YPAD + lane] = a2;
  }

  // ---- per-wave stats: 60 lanes, 16 rows each, then 2 shuffle levels ----
  if (lane < 60) {
    int fl = lane >> 2, c = lane & 3;
    const float* yp = ytq + fl * YPAD + c * 16;
    float s1 = 0.f, s2 = 0.f;
    #pragma unroll
    for (int i = 0; i < 16; ++i) {
      float v = yp[i];
      s1 += v;
      s2 = fmaf(v, v, s2);
    }
    s1 += __shfl_xor(s1, 1, 64); s2 += __shfl_xor(s2, 1, 64);
    s1 += __shfl_xor(s1, 2, 64); s2 += __shfl_xor(s2, 2, 64);
    int gf = fbase + fl;
    if (c == 0 && gf < F) {
      double* slot = acc + ((size_t)gf * NSLC + slice) * 2;
      atomicAdd(slot,     (double)s1);               // hw f64 atomic
      atomicAdd(slot + 1, (double)s2);
    }
  }
}

// ---------------------------------------------------------------------------
// Final BN: hT -> row-major out via LDS transpose tile (64 rows/block).
// ---------------------------------------------------------------------------
__global__ void __launch_bounds__(NTHR, 4)
final_tr_kernel(const float* __restrict__ hT, const double* __restrict__ acc_last,
                const float* __restrict__ g, const float* __restrict__ bt,
                float* __restrict__ out)
{
  __shared__ float2 scsh[64];
  __shared__ float  ybuf[RPB * 61];
  const int tid = threadIdx.x;
  make_scsh(acc_last, g, bt, scsh, tid);

  const int rowbase = blockIdx.x * RPB;
  for (int i = tid; i < F * RPB; i += NTHR) {
    int j = i >> 6, r = i & 63;
    float2 s = scsh[j];
    ybuf[r * 61 + j] = fmaf(hT[(size_t)j * B + rowbase + r], s.x, s.y);
  }
  __syncthreads();

  float* oblk = out + (size_t)rowbase * F;
  for (int i = tid; i < RPB * F; i += NTHR) {
    int r = i / F, j = i - r * F;
    oblk[i] = ybuf[r * 61 + j];
  }
}

// ---------------------------------------------------------------------------
extern "C" void kernel_launch(void* const* d_in, const int* in_sizes, int n_in,
                              void* d_out, int out_size, void* d_ws, size_t ws_size,
                              hipStream_t stream)
{
  const float* x   = (const float*)d_in[0];
  const float* W0  = (const float*)d_in[1];
  const float* b0  = (const float*)d_in[2];
  const float* g0  = (const float*)d_in[3];
  const float* bt0 = (const float*)d_in[4];
  const float* Ws  = (const float*)d_in[5];
  const float* bs  = (const float*)d_in[6];
  const float* gs  = (const float*)d_in[7];
  const float* bts = (const float*)d_in[8];
  float* out = (float*)d_out;

  double* acc = (double*)d_ws;                       // [NB][F][NSLC][2]
  float*  hT  = (float*)((char*)d_ws + HT_OFF_B);    // [F][B]

  // zero the atomic accumulators every call (deterministic, capture-safe)
  hipMemsetAsync(d_ws, 0, (size_t)ACC_TOTAL * sizeof(double), stream);

  // layer 0: x[B,29] -> hT[59][B]
  layer_kernel<K0, true><<<NBLK, NTHR, 0, stream>>>(
      x, W0, b0, nullptr, nullptr, nullptr, hT, acc);

  // layers 1..14: hT -> hT (each block reads its rows before writing them)
  for (int b = 1; b < NB; ++b) {
    const float* gp  = (b == 1) ? g0  : gs  + (size_t)(b - 2) * F;
    const float* btp = (b == 1) ? bt0 : bts + (size_t)(b - 2) * F;
    layer_kernel<F, false><<<NBLK, NTHR, 0, stream>>>(
        hT, Ws + (size_t)(b - 1) * F * F, bs + (size_t)(b - 1) * F,
        acc + (size_t)(b - 1) * ACC_PER_LAYER, gp, btp,
        hT, acc + (size_t)b * ACC_PER_LAYER);
  }

  // apply layer 14's BN: hT -> row-major d_out
  final_tr_kernel<<<NBLK, NTHR, 0, stream>>>(
      hT, acc + (size_t)(NB - 1) * ACC_PER_LAYER,
      gs + (size_t)(NB - 2) * F, bts + (size_t)(NB - 2) * F, out);
}

// Round 10
// 701.363 us; speedup vs baseline: 1.2396x; 1.2070x over previous
//
#include <hip/hip_runtime.h>

#define NTHR  256
#define F     59
#define K0    29
#define NB    15
#define B     131072
#define RPB   64                 // rows per block
#define NBLK  (B / RPB)          // 2048 blocks
#define NSLC  32                 // f64 atomic slices; 16B slot per (feature,slice)

// d_ws layout: acc[NB][F][NSLC][2] doubles, then hB[F][B] floats.
// (hA lives in d_out, which is dead until the final kernel.)
#define ACC_PER_LAYER (F * NSLC * 2)            // 3776 doubles / layer
#define ACC_TOTAL     (NB * ACC_PER_LAYER)      // 56640 doubles = 453120 B
#define HB_OFF_B      ((size_t)ACC_TOTAL * 8)

// ---------------------------------------------------------------------------
// Finalize previous layer's stats (fp64) into LDS {scale, shift} (float2).
// Runs redundantly in every block; acc_prev complete by stream order.
// ---------------------------------------------------------------------------
__device__ __forceinline__ void make_scsh(const double* __restrict__ acc_prev,
                                          const float* __restrict__ g,
                                          const float* __restrict__ bt,
                                          float2* scsh, int tid)
{
  if (tid < F) {
    double s1 = 0.0, s2 = 0.0;
    #pragma unroll
    for (int s = 0; s < NSLC; ++s) {
      const double* p = acc_prev + ((size_t)tid * NSLC + s) * 2;
      s1 += p[0];
      s2 += p[1];
    }
    const double inv = 1.0 / (double)B;
    double mu   = s1 * inv;
    double var  = fma(s2, inv, -mu * mu);        // biased variance, fp64
    double rstd = 1.0 / sqrt(var + 1e-5);
    double sc   = rstd * (double)g[tid];
    scsh[tid] = make_float2((float)sc, (float)fma(-mu, sc, (double)bt[tid]));
  }
  __syncthreads();
}

// ---------------------------------------------------------------------------
// One Linear+ReLU layer. Block = 64 rows (row = lane); wave q owns features
// q*15..q*15+14 (wave 3: 14 real + 1 clamped dup). Pipeline per block:
//   stage h to LDS once (coalesced, normalize-on-copy) -> h to 59 registers
//   -> j-outer/k-inner FMA (W rows contiguous: batched s_load feeding
//   v_fmac's scalar operand) -> coalesced y stores -> 15-feature butterfly
//   stats (ILP across features) -> sliced f64 atomics.
// ---------------------------------------------------------------------------
template<int K, bool FIRST>
__global__ void __launch_bounds__(NTHR, 4)
layer_kernel(const float* __restrict__ in, const float* __restrict__ W,
             const float* __restrict__ bvec,
             const double* __restrict__ acc_prev,    // prev stats (unless FIRST)
             const float* __restrict__ g_prev, const float* __restrict__ bt_prev,
             float* __restrict__ hout, double* acc)
{
  __shared__ float  hbuf[FIRST ? (K0 * 66) : (K * 64)];
  __shared__ float2 scsh[64];

  const int tid   = threadIdx.x;
  const int lane  = tid & 63;
  const int qu    = __builtin_amdgcn_readfirstlane(tid >> 6);
  const int rowbase = blockIdx.x * RPB;
  const int slice   = blockIdx.x & (NSLC - 1);

  if (!FIRST) make_scsh(acc_prev, g_prev, bt_prev, scsh, tid);

  // ---- stage the block's 64 input rows into LDS, exactly once ----
  if (FIRST) {
    // x is row-major [B][K]: read coalesced, write [k][66] (2-way conflict ok)
    const float* xblk = in + (size_t)rowbase * K;
    #pragma unroll 4
    for (int i = tid; i < RPB * K; i += NTHR) {
      int r = i / K, k = i - r * K;
      hbuf[k * 66 + r] = xblk[i];
    }
  } else {
    // hT is [F][B]: read coalesced (one k per wave-iter), write [k][64]
    #pragma unroll 4
    for (int i = tid; i < K * 64; i += NTHR) {
      int k = i >> 6, r = i & 63;
      float2 s = scsh[k];
      hbuf[i] = fmaf(in[(size_t)k * B + rowbase + r], s.x, s.y);
    }
  }
  __syncthreads();

  // ---- h row -> registers (59 VGPRs), conflict-free LDS reads ----
  float h[K];
  #pragma unroll
  for (int k = 0; k < K; ++k)
    h[k] = FIRST ? hbuf[k * 66 + lane] : hbuf[k * 64 + lane];

  // ---- j-outer / k-inner: W contiguous per row -> scalar-operand FMAs ----
  const int fbase = qu * 15;
  float y[15];
  #pragma unroll
  for (int j = 0; j < 15; ++j) {
    int wrow = fbase + j;
    wrow = wrow > F - 1 ? F - 1 : wrow;              // scalar clamp (wave 3)
    const float* wp = W + (size_t)wrow * K;
    float a = bvec[wrow];
    #pragma unroll
    for (int k = 0; k < K; ++k) a = fmaf(h[k], wp[k], a);
    y[j] = fmaxf(a, 0.f);
  }

  // ---- coalesced stores to the pong buffer ----
  float* op = hout + rowbase + lane;
  #pragma unroll
  for (int j = 0; j < 15; ++j) {
    int f = fbase + j;
    if (f < F) op[(size_t)f * B] = y[j];             // uniform guard
  }

  // ---- stats: 15 butterflies with cross-feature ILP ----
  float ms = 0.f, mss = 0.f;
  #pragma unroll
  for (int j = 0; j < 15; ++j) {
    if (fbase + j < F) {                             // uniform guard
      float s = y[j], ss = y[j] * y[j];
      #pragma unroll
      for (int m = 1; m < 64; m <<= 1) {
        s  += __shfl_xor(s,  m, 64);
        ss += __shfl_xor(ss, m, 64);
      }
      if (lane == j) { ms = s; mss = ss; }
    }
  }
  if (lane < 15 && fbase + lane < F) {
    double* slot = acc + ((size_t)(fbase + lane) * NSLC + slice) * 2;
    atomicAdd(slot,     (double)ms);                 // hw f64 atomic
    atomicAdd(slot + 1, (double)mss);
  }
}

// ---------------------------------------------------------------------------
// Final BN: hT -> row-major out via LDS transpose tile (64 rows/block).
// ---------------------------------------------------------------------------
__global__ void __launch_bounds__(NTHR, 4)
final_tr_kernel(const float* __restrict__ hT, const double* __restrict__ acc_last,
                const float* __restrict__ g, const float* __restrict__ bt,
                float* __restrict__ out)
{
  __shared__ float2 scsh[64];
  __shared__ float  ybuf[RPB * 61];
  const int tid = threadIdx.x;
  make_scsh(acc_last, g, bt, scsh, tid);

  const int rowbase = blockIdx.x * RPB;
  for (int i = tid; i < F * RPB; i += NTHR) {
    int j = i >> 6, r = i & 63;
    float2 s = scsh[j];
    ybuf[r * 61 + j] = fmaf(hT[(size_t)j * B + rowbase + r], s.x, s.y);
  }
  __syncthreads();

  float* oblk = out + (size_t)rowbase * F;
  for (int i = tid; i < RPB * F; i += NTHR) {
    int r = i / F, j = i - r * F;
    oblk[i] = ybuf[r * 61 + j];
  }
}

// ---------------------------------------------------------------------------
extern "C" void kernel_launch(void* const* d_in, const int* in_sizes, int n_in,
                              void* d_out, int out_size, void* d_ws, size_t ws_size,
                              hipStream_t stream)
{
  const float* x   = (const float*)d_in[0];
  const float* W0  = (const float*)d_in[1];
  const float* b0  = (const float*)d_in[2];
  const float* g0  = (const float*)d_in[3];
  const float* bt0 = (const float*)d_in[4];
  const float* Ws  = (const float*)d_in[5];
  const float* bs  = (const float*)d_in[6];
  const float* gs  = (const float*)d_in[7];
  const float* bts = (const float*)d_in[8];
  float* out = (float*)d_out;

  double* acc = (double*)d_ws;                       // [NB][F][NSLC][2]
  float*  hB  = (float*)((char*)d_ws + HB_OFF_B);    // [F][B] in workspace
  float*  hA  = out;                                 // [F][B] alias of d_out

  // zero the atomic accumulators every call (deterministic, capture-safe)
  hipMemsetAsync(d_ws, 0, (size_t)ACC_TOTAL * sizeof(double), stream);

  // layer 0: x[B,29] -> hB
  layer_kernel<K0, true><<<NBLK, NTHR, 0, stream>>>(
      x, W0, b0, nullptr, nullptr, nullptr, hB, acc);

  // layers 1..14: ping-pong hB <-> hA (d_out), normalize-prev-on-read
  for (int b = 1; b < NB; ++b) {
    const float* gp  = (b == 1) ? g0  : gs  + (size_t)(b - 2) * F;
    const float* btp = (b == 1) ? bt0 : bts + (size_t)(b - 2) * F;
    const float* src = (b & 1) ? hB : hA;
    float*       dst = (b & 1) ? hA : hB;
    layer_kernel<F, false><<<NBLK, NTHR, 0, stream>>>(
        src, Ws + (size_t)(b - 1) * F * F, bs + (size_t)(b - 1) * F,
        acc + (size_t)(b - 1) * ACC_PER_LAYER, gp, btp,
        dst, acc + (size_t)b * ACC_PER_LAYER);
  }

  // layer 14 wrote hB (14 even) -> final BN into row-major d_out
  final_tr_kernel<<<NBLK, NTHR, 0, stream>>>(
      hB, acc + (size_t)(NB - 1) * ACC_PER_LAYER,
      gs + (size_t)(NB - 2) * F, bts + (size_t)(NB - 2) * F, out);
}